// Round 1
// baseline (27.138 us; speedup 1.0000x reference)
//
#include <hip/hip_runtime.h>

#define POOL 7
#define NUM_ROIS 300
#define CHANNELS 512
#define IMG_W 256

// One block per (roi, py, px); 128 threads, each handling 4 channels (float4).
__global__ __launch_bounds__(128) void roi_align_kernel(
    const float* __restrict__ img,   // (256,256,512)
    const int* __restrict__ rois,    // (300,4) x,y,w,h
    float* __restrict__ out)         // (300,7,7,512)
{
    const int bid = blockIdx.x;                 // 0 .. 300*49-1
    const int r   = bid / (POOL * POOL);
    const int pp  = bid % (POOL * POOL);
    const int py  = pp / POOL;
    const int px  = pp % POOL;

    const int x = rois[r * 4 + 0];
    const int y = rois[r * 4 + 1];
    const int w = rois[r * 4 + 2];
    const int h = rois[r * 4 + 3];

    // y axis coords (matches _axis_coords in fp32)
    float scy  = (float)h / (float)POOL;
    float srcy = ((float)py + 0.5f) * scy - 0.5f;
    srcy = fminf(fmaxf(srcy, 0.0f), (float)h - 1.0f);
    int   iy0 = (int)floorf(srcy);
    int   iy1 = min(iy0 + 1, h - 1);
    float fy  = srcy - (float)iy0;
    const int y0 = y + iy0, y1 = y + iy1;

    // x axis coords
    float scx  = (float)w / (float)POOL;
    float srcx = ((float)px + 0.5f) * scx - 0.5f;
    srcx = fminf(fmaxf(srcx, 0.0f), (float)w - 1.0f);
    int   ix0 = (int)floorf(srcx);
    int   ix1 = min(ix0 + 1, w - 1);
    float fx  = srcx - (float)ix0;
    const int x0 = x + ix0, x1 = x + ix1;

    const float4* p00 = (const float4*)(img + ((size_t)y0 * IMG_W + x0) * CHANNELS);
    const float4* p01 = (const float4*)(img + ((size_t)y0 * IMG_W + x1) * CHANNELS);
    const float4* p10 = (const float4*)(img + ((size_t)y1 * IMG_W + x0) * CHANNELS);
    const float4* p11 = (const float4*)(img + ((size_t)y1 * IMG_W + x1) * CHANNELS);
    float4* po = (float4*)(out + (((size_t)r * POOL + py) * POOL + px) * CHANNELS);

    const int t = threadIdx.x;  // 0..127 -> channels 4t..4t+3

    float4 a = p00[t];
    float4 b = p01[t];
    float4 c = p10[t];
    float4 d = p11[t];

    const float gx = 1.0f - fx;
    const float gy = 1.0f - fy;

    // rows0 = a*(1-fx) + b*fx ; rows1 = c*(1-fx) + d*fx ; out = rows0*(1-fy) + rows1*fy
    float4 o;
    o.x = (a.x * gx + b.x * fx) * gy + (c.x * gx + d.x * fx) * fy;
    o.y = (a.y * gx + b.y * fx) * gy + (c.y * gx + d.y * fx) * fy;
    o.z = (a.z * gx + b.z * fx) * gy + (c.z * gx + d.z * fx) * fy;
    o.w = (a.w * gx + b.w * fx) * gy + (c.w * gx + d.w * fx) * fy;

    po[t] = o;
}

extern "C" void kernel_launch(void* const* d_in, const int* in_sizes, int n_in,
                              void* d_out, int out_size, void* d_ws, size_t ws_size,
                              hipStream_t stream) {
    const float* img  = (const float*)d_in[0];
    const int*   rois = (const int*)d_in[1];
    float*       out  = (float*)d_out;

    const int nblocks = NUM_ROIS * POOL * POOL;  // 14700
    roi_align_kernel<<<nblocks, 128, 0, stream>>>(img, rois, out);
}

// Round 3
// 27.055 us; speedup vs baseline: 1.0031x; 1.0031x over previous
//
#include <hip/hip_runtime.h>

#define POOL 7
#define NUM_ROIS 300
#define CHANNELS 512
#define IMG_W 256

typedef float f32x4 __attribute__((ext_vector_type(4)));

// One block per (roi, py); 128 threads; each thread handles 4 channels (f32x4)
// for all 7 px cells of the row. 28 independent loads in flight per thread.
__global__ __launch_bounds__(128) void roi_align_row_kernel(
    const float* __restrict__ img,   // (256,256,512)
    const int* __restrict__ rois,    // (300,4) x,y,w,h
    float* __restrict__ out)         // (300,7,7,512)
{
    const int bid = blockIdx.x;      // 0 .. 2099
    const int r   = bid / POOL;
    const int py  = bid % POOL;

    const int x = rois[r * 4 + 0];
    const int y = rois[r * 4 + 1];
    const int w = rois[r * 4 + 2];
    const int h = rois[r * 4 + 3];

    // y axis coords for this py (fp32, matches _axis_coords)
    float scy  = (float)h / (float)POOL;
    float srcy = ((float)py + 0.5f) * scy - 0.5f;
    srcy = fminf(fmaxf(srcy, 0.0f), (float)h - 1.0f);
    int   iy0 = (int)floorf(srcy);
    int   iy1 = min(iy0 + 1, h - 1);
    const float fy = srcy - (float)iy0;
    const float gy = 1.0f - fy;
    const size_t row0 = (size_t)(y + iy0) * IMG_W;
    const size_t row1 = (size_t)(y + iy1) * IMG_W;

    // x axis coords for all 7 px (same for every thread in block)
    const float scx = (float)w / (float)POOL;
    int   x0[POOL], x1[POOL];
    float fx[POOL];
#pragma unroll
    for (int px = 0; px < POOL; ++px) {
        float srcx = ((float)px + 0.5f) * scx - 0.5f;
        srcx = fminf(fmaxf(srcx, 0.0f), (float)w - 1.0f);
        int i0 = (int)floorf(srcx);
        int i1 = min(i0 + 1, w - 1);
        fx[px] = srcx - (float)i0;
        x0[px] = x + i0;
        x1[px] = x + i1;
    }

    const int t = threadIdx.x;  // channels 4t..4t+3

    // Phase 1: issue all 28 corner loads (independent -> deep MLP)
    f32x4 a[POOL], b[POOL], c[POOL], d[POOL];
#pragma unroll
    for (int px = 0; px < POOL; ++px) {
        a[px] = ((const f32x4*)(img + (row0 + (size_t)x0[px]) * CHANNELS))[t];
        b[px] = ((const f32x4*)(img + (row0 + (size_t)x1[px]) * CHANNELS))[t];
        c[px] = ((const f32x4*)(img + (row1 + (size_t)x0[px]) * CHANNELS))[t];
        d[px] = ((const f32x4*)(img + (row1 + (size_t)x1[px]) * CHANNELS))[t];
    }

    // Phase 2: blend + nontemporal store (output never re-read)
    f32x4* po = (f32x4*)(out + ((size_t)r * POOL + py) * POOL * CHANNELS);
#pragma unroll
    for (int px = 0; px < POOL; ++px) {
        const float f = fx[px], g = 1.0f - f;
        f32x4 o = (a[px] * g + b[px] * f) * gy + (c[px] * g + d[px] * f) * fy;
        __builtin_nontemporal_store(o, &po[px * (CHANNELS / 4) + t]);
    }
}

extern "C" void kernel_launch(void* const* d_in, const int* in_sizes, int n_in,
                              void* d_out, int out_size, void* d_ws, size_t ws_size,
                              hipStream_t stream) {
    const float* img  = (const float*)d_in[0];
    const int*   rois = (const int*)d_in[1];
    float*       out  = (float*)d_out;

    const int nblocks = NUM_ROIS * POOL;  // 2100
    roi_align_row_kernel<<<nblocks, 128, 0, stream>>>(img, rois, out);
}